// Round 12
// baseline (585.209 us; speedup 1.0000x reference)
//
#include <hip/hip_runtime.h>
#include <hip/hip_bf16.h>

typedef unsigned short u16;
typedef __bf16 bf16x8 __attribute__((ext_vector_type(8)));
typedef float  f32x4  __attribute__((ext_vector_type(4)));

__device__ __forceinline__ float b2f(u16 u){
  union{ unsigned int i; float f; } a; a.i = ((unsigned int)u)<<16; return a.f;
}
__device__ __forceinline__ u16 f2b(float f){
  __hip_bfloat16 h = __float2bfloat16(f);
  u16 r; __builtin_memcpy(&r, &h, 2); return r;
}
__device__ __forceinline__ int imin(int a,int b){ return a<b?a:b; }

// async global->LDS, 16B per lane: HW writes ldsbase + lane*16.
__device__ __forceinline__ void gl_lds16(const void* g, void* l){
  __builtin_amdgcn_global_load_lds(
      (const __attribute__((address_space(1))) void*)g,
      (__attribute__((address_space(3))) void*)l, 16, 0, 0);
}
__device__ __forceinline__ void vm_drain(){
  asm volatile("s_waitcnt vmcnt(0)" ::: "memory");
}
__device__ __forceinline__ void vm_wait4(){
  asm volatile("s_waitcnt vmcnt(4)" ::: "memory");
}

// ---------------------------------------------------------------------------
// 128x128 MFMA GEMM: C[M,N] = A[M,K]bf16 @ Wt[N,K]bf16^T.
// OUTMODE: 0 fp32, 1 bf16, 2 bf16+relu. CAT: k<256 A, k>=256 A2 (stride 256).
// NSEL: up to 3 independent GEMMs in one launch; bz selects (A,W,out).
// XCD remap for A-tile L2 reuse (NB divisible by 8 at all call sites).
// LDS XOR swizzle (src pre-swizzled, read XOR). Triple-buffer + vmcnt(4).
// ---------------------------------------------------------------------------
template<int KD, int OUTMODE, bool CAT, int NSEL>
__global__ __launch_bounds__(256) void gemm128(
    const u16* __restrict__ A, const u16* __restrict__ A2, const u16* __restrict__ A3,
    const u16* __restrict__ Wt, const u16* __restrict__ Wt2, const u16* __restrict__ Wt3,
    float* __restrict__ Cf, u16* __restrict__ Cb, u16* __restrict__ Cb2, u16* __restrict__ Cb3,
    int NDIM, int aoff)
{
  __shared__ u16 At[3][128*32];
  __shared__ u16 Bt[3][128*32];
  const int tid = threadIdx.x;
  const int ny = gridDim.y, nz = gridDim.z;
  const int NB = gridDim.x*ny*nz;
  const int L  = blockIdx.x + gridDim.x*(blockIdx.y + ny*blockIdx.z);
  const int cpx = NB >> 3;
  const int wkid = (L & 7)*cpx + (L >> 3);
  const int nc = ny*nz;
  const int bx = wkid / nc;
  const int cc_ = wkid - bx*nc;
  const int by = cc_ % ny;
  const int bz = cc_ / ny;

  const u16* Aa = (NSEL>=3 && bz==2) ? A3 : A;
  const u16* W  = (NSEL>=2 && bz==1) ? Wt2 : ((NSEL>=3 && bz==2) ? Wt3 : Wt);
  u16* Cbo      = (NSEL>=2 && bz==1) ? Cb2 : ((NSEL>=3 && bz==2) ? Cb3 : Cb);
  const int w = tid>>6, lane = tid&63;
  const int q4 = lane>>4, l15 = lane&15;
  const int wr = w>>1, wc = w&1;
  const int rstage = lane>>2;
  const int kcol = (((lane&3) ^ ((lane>>2)&3))<<3);
  const size_t arow0 = (size_t)(aoff + bx*128);
  const int n0 = by*128;

  f32x4 acc[4][4];
  #pragma unroll
  for (int i=0;i<4;i++)
    #pragma unroll
    for (int j=0;j<4;j++){ acc[i][j][0]=0.f; acc[i][j][1]=0.f; acc[i][j][2]=0.f; acc[i][j][3]=0.f; }

  auto stage = [&](int k0, int buf){
    #pragma unroll
    for (int j=0;j<2;j++){
      const int trow = w*32 + j*16 + rstage;
      const u16* ga;
      if (CAT){
        ga = (k0<256) ? (A  + (arow0+trow)*256 + k0 + kcol)
                      : (A2 + (arow0+trow)*256 + (k0-256) + kcol);
      } else {
        ga = Aa + (arow0+trow)*(size_t)KD + k0 + kcol;
      }
      gl_lds16(ga, &At[buf][(w*32+j*16)*32]);
      const u16* gb = W + (size_t)(n0 + trow)*KD + k0 + kcol;
      gl_lds16(gb, &Bt[buf][(w*32+j*16)*32]);
    }
  };

  constexpr int NK = KD/32;            // >= 8 for all instantiations
  stage(0, 0);
  stage(32, 1);
  vm_wait4();                          // tile 0 landed; tile 1 in flight
  __builtin_amdgcn_s_barrier();
  int cb = 0;                          // compute-buffer index (t % 3)
  for (int t=0; t<NK; ++t){
    if (t+2 < NK){
      int sbuf = cb ? cb-1 : 2;        // (t+2) % 3
      stage((t+2)*32, sbuf);
    }
    bf16x8 af[4], bv[4];
    #pragma unroll
    for (int i=0;i<4;i++){
      __builtin_memcpy(&af[i], &At[cb][(wr*64 + i*16 + l15)*32 + ((q4^(l15&3))<<3)], 16);
      __builtin_memcpy(&bv[i], &Bt[cb][(wc*64 + i*16 + l15)*32 + ((q4^(l15&3))<<3)], 16);
    }
    #pragma unroll
    for (int i=0;i<4;i++)
      #pragma unroll
      for (int j=0;j<4;j++)
        acc[i][j] = __builtin_amdgcn_mfma_f32_16x16x32_bf16(af[i], bv[j], acc[i][j], 0,0,0);
    if (t+1 < NK){
      if (t+2 < NK) vm_wait4(); else vm_drain();
      __builtin_amdgcn_s_barrier();
      cb = (cb==2)? 0 : cb+1;
    }
  }
  #pragma unroll
  for (int i=0;i<4;i++){
    const int row0 = bx*128 + wr*64 + i*16 + q4*4;
    #pragma unroll
    for (int j=0;j<4;j++){
      const int col = n0 + wc*64 + j*16 + l15;
      #pragma unroll
      for (int r=0;r<4;r++){
        float v = acc[i][j][r];
        size_t idx = (size_t)(row0+r)*NDIM + col;
        if (OUTMODE==0) Cf[idx]=v;
        else if (OUTMODE==1) Cbo[idx]=f2b(v);
        else Cbo[idx]=f2b(v>0.f?v:0.f);
      }
    }
  }
}

// fp32 -> bf16 hi + lo residual, two tensors in one launch (grid 2*n/1024)
__global__ __launch_bounds__(256) void cvt_split2(
    const float* __restrict__ inA, u16* __restrict__ ohA, u16* __restrict__ olA,
    const float* __restrict__ inB, u16* __restrict__ ohB, u16* __restrict__ olB, int n){
  int i = (blockIdx.x*256 + threadIdx.x)*4;
  const float* in; u16 *oh, *ol; int j;
  if (i < n){ in=inA; oh=ohA; ol=olA; j=i; }
  else      { in=inB; oh=ohB; ol=olB; j=i-n; }
  float4 f = *(const float4*)(in+j);
  float v[4]={f.x,f.y,f.z,f.w};
  #pragma unroll
  for (int t=0;t<4;t++){ u16 h=f2b(v[t]); oh[j+t]=h; ol[j+t]=f2b(v[t]-b2f(h)); }
}

// four 256x256 transposes in one launch, grid (256,4)
__global__ __launch_bounds__(256) void wtrans4(
    const float* __restrict__ W0, const float* __restrict__ W1,
    const float* __restrict__ W2, const float* __restrict__ W3,
    u16* __restrict__ T0, u16* __restrict__ T1,
    u16* __restrict__ T2, u16* __restrict__ T3)
{
  const int g = blockIdx.y;
  const float* W = g==0?W0:(g==1?W1:(g==2?W2:W3));
  u16* T = g==0?T0:(g==1?T1:(g==2?T2:T3));
  int idx = blockIdx.x*256 + threadIdx.x;
  int nn = idx>>8, kk = idx&255;
  T[idx] = f2b(W[(size_t)kk*256 + nn]);
}

// Wm1 [512,512] and Wm2 [512,256] transposes in one launch, grid 1536
__global__ __launch_bounds__(256) void wtrans2(
    const float* __restrict__ W1, u16* __restrict__ T1,
    const float* __restrict__ W2, u16* __restrict__ T2)
{
  int idx = blockIdx.x*256 + threadIdx.x;
  if (idx < 512*512){
    int nn = idx>>9, kk = idx&511;
    T1[idx] = f2b(W1[(size_t)kk*512 + nn]);
  } else {
    int j = idx - 512*512;           // 0..131071, N=256 K=512
    int nn = j>>9, kk = j&511;
    T2[j] = f2b(W2[(size_t)kk*256 + nn]);
  }
}

// ---------------------------------------------------------------------------
// L2 warm for the decoder chain weights: 8 consecutive blocks read the SAME
// 1KB-per-thread slice (one block per XCD by round-robin dispatch), pulling a
// full copy of all 7 weights into every XCD's private L2. grid 3584.
// ---------------------------------------------------------------------------
__global__ __launch_bounds__(256) void warm7(
    const float* __restrict__ W0, const float* __restrict__ W1,
    const float* __restrict__ W2, const float* __restrict__ W3,
    const float* __restrict__ W4, const float* __restrict__ W5,
    const float* __restrict__ W6, float* __restrict__ scratch)
{
  const int slice = blockIdx.x >> 3;            // 0..447
  const int wsel = slice >> 6;                  // weight 0..6
  const int off = ((slice & 63)<<8) + threadIdx.x;  // float4 index
  const float* W = wsel==0?W0:wsel==1?W1:wsel==2?W2:wsel==3?W3:wsel==4?W4:wsel==5?W5:W6;
  float4 v = ((const float4*)W)[off];
  float s = v.x+v.y+v.z+v.w;
  if (s == 1234567.891f) scratch[blockIdx.x] = s;   // keeps loads live, never taken
}

// ---------------------------------------------------------------------------
// Logits GEMM v2 (dual): Out[l,np] = A[l,:].M[:,np] via hi/lo bf16 (hh+hl+lh).
// blockIdx.y selects the (A,B,Out) set (q vs k). Triple-buffer counted-vmcnt.
// ---------------------------------------------------------------------------
__global__ __launch_bounds__(256) void gemm_logits2(
    const u16* __restrict__ Ah0, const u16* __restrict__ Al0,
    const u16* __restrict__ Bh0, const u16* __restrict__ Bl0,
    float* __restrict__ O0,
    const u16* __restrict__ Ah1, const u16* __restrict__ Al1,
    const u16* __restrict__ Bh1, const u16* __restrict__ Bl1,
    float* __restrict__ O1)
{
  __shared__ u16 SA[3][64*32], SAL[3][64*32], SB[3][64*32], SBL[3][64*32];
  const int tid=threadIdx.x, bx=blockIdx.x;
  const int sel = blockIdx.y;
  const u16* Ah = sel? Ah1:Ah0;  const u16* Al = sel? Al1:Al0;
  const u16* BhT= sel? Bh1:Bh0;  const u16* BlT= sel? Bl1:Bl0;
  float* Out = sel? O1:O0;
  const int w=tid>>6, lane=tid&63, q4=lane>>4, l15=lane&15;
  const int bloc = bx/75;
  const u16* bh_ = BhT + (size_t)bloc*16384;
  const u16* bl_ = BlT + (size_t)bloc*16384;
  const size_t arow0 = (size_t)bx*64;
  const int rsub = lane>>2;
  const int csub = (((lane&3) ^ ((lane>>2)&3))<<3);
  f32x4 acc[4];
  #pragma unroll
  for (int t=0;t<4;t++){ acc[t][0]=0.f; acc[t][1]=0.f; acc[t][2]=0.f; acc[t][3]=0.f; }

  auto stage = [&](int k0, int buf){
    #pragma unroll
    for (int i=0;i<4;i++){
      const int row = i*16 + rsub;
      if (w==0)      gl_lds16(Ah + (arow0+row)*256 + k0 + csub, &SA [buf][i*16*32]);
      else if (w==1) gl_lds16(Al + (arow0+row)*256 + k0 + csub, &SAL[buf][i*16*32]);
      else if (w==2) gl_lds16(bh_ + (size_t)row*256 + k0 + csub, &SB [buf][i*16*32]);
      else           gl_lds16(bl_ + (size_t)row*256 + k0 + csub, &SBL[buf][i*16*32]);
    }
  };

  stage(0, 0);
  stage(32, 1);
  vm_wait4();
  __builtin_amdgcn_s_barrier();
  int cb = 0;
  for (int t=0;t<8;++t){
    if (t+2 < 8){
      int sbuf = cb ? cb-1 : 2;
      stage((t+2)*32, sbuf);
    }
    bf16x8 ah, al;
    __builtin_memcpy(&ah, &SA [cb][(w*16+l15)*32 + ((q4^(l15&3))<<3)], 16);
    __builtin_memcpy(&al, &SAL[cb][(w*16+l15)*32 + ((q4^(l15&3))<<3)], 16);
    #pragma unroll
    for (int nt=0;nt<4;nt++){
      bf16x8 bh, bl;
      __builtin_memcpy(&bh, &SB [cb][(nt*16+l15)*32 + ((q4^(l15&3))<<3)], 16);
      __builtin_memcpy(&bl, &SBL[cb][(nt*16+l15)*32 + ((q4^(l15&3))<<3)], 16);
      acc[nt] = __builtin_amdgcn_mfma_f32_16x16x32_bf16(ah, bh, acc[nt], 0,0,0);
      acc[nt] = __builtin_amdgcn_mfma_f32_16x16x32_bf16(ah, bl, acc[nt], 0,0,0);
      acc[nt] = __builtin_amdgcn_mfma_f32_16x16x32_bf16(al, bh, acc[nt], 0,0,0);
    }
    if (t+1 < 8){
      if (t+2 < 8) vm_wait4(); else vm_drain();
      __builtin_amdgcn_s_barrier();
      cb = (cb==2)? 0 : cb+1;
    }
  }
  #pragma unroll
  for (int nt=0;nt<4;nt++)
    #pragma unroll
    for (int r=0;r<4;r++)
      Out[(arow0 + w*16 + q4*4 + r)*64 + nt*16 + l15] = acc[nt][r];
}

// ---------------------------------------------------------------------------
// MFMA KV reduce: KV[bh,d,v] += sum_s K'[s,d]*V[s,v]; Ks[bh,d] += sum_s K'[s,d]
// KSM (DKT=8, KF32): K' = row-softmax(logits)*col-softmax + 1, computed inline.
// ---------------------------------------------------------------------------
template<int DKT, bool ELU, bool KF32, bool KSM>
__global__ __launch_bounds__(256) void la_reduce_mfma(
    const void* __restrict__ Kv, int kstride, const u16* __restrict__ Vv,
    float* __restrict__ KV, float* __restrict__ Ks, int Skv,
    const float* __restrict__ cmax, const float* __restrict__ csum)
{
  constexpr int PAD = 136;               // u16 row stride (272B: 16B-aligned)
  constexpr int MROW = (DKT<16)?16:DKT;
  __shared__ u16 Klt[MROW*PAD];
  __shared__ u16 Vlt[32*PAD];
  __shared__ float Ksl[DKT];
  const int tid = threadIdx.x;
  const int bh = blockIdx.y; const int b = bh>>3, h = bh&7;
  const int s0 = blockIdx.x*256;
  if (tid < DKT) Ksl[tid] = 0.f;

  const int w = tid>>6, lane = tid&63, q4 = lane>>4, l15 = lane&15;
  constexpr int NT = (DKT==32)?4:2;      // 16x16 output tiles
  const int tileid = w % NT;
  const int mt = (DKT==32)? (tileid>>1) : 0;
  const int nt = (DKT==32)? (tileid&1) : tileid;
  constexpr int KPER = (DKT==32)?4:2;    // ksteps per wave
  const int k0w = (w/NT)*KPER;

  const int kd = tid & (DKT-1);
  const int ksrow = tid / DKT;           // DKT=32: 0..7; DKT=8: 0..31
  const int ksstep = 256/DKT;
  const int vv = tid & 31, vsrow = tid >> 5;

  f32x4 acc; acc[0]=0.f; acc[1]=0.f; acc[2]=0.f; acc[3]=0.f;
  float kacc = 0.f;

  for (int cc=0; cc<2; cc++){
    const int sc0 = s0 + cc*128;
    // ---- stage K' transposed ----
    if constexpr (KSM){
      #pragma unroll
      for (int t=0; t<4; t++){
        int s = ksrow + t*32;
        float xv = 0.f;
        if (sc0+s < Skv){
          const float* rowp = (const float*)Kv + ((size_t)b*Skv + sc0+s)*64;
          float vals[8];
          #pragma unroll
          for (int j=0;j<8;j++) vals[j] = rowp[kd + 8*j];
          float m = vals[0];
          #pragma unroll
          for (int j=1;j<8;j++) m = fmaxf(m, vals[j]);
          #pragma unroll
          for (int off=1;off<8;off<<=1) m = fmaxf(m, __shfl_xor(m, off));
          float ssum = 0.f;
          #pragma unroll
          for (int j=0;j<8;j++) ssum += __expf(vals[j]-m);
          #pragma unroll
          for (int off=1;off<8;off<<=1) ssum += __shfl_xor(ssum, off);
          float vneed = vals[0];
          #pragma unroll
          for (int j=1;j<8;j++) if (h==j) vneed = vals[j];
          const int np = h*8 + kd;
          float cs = __expf(vneed - cmax[(size_t)b*64+np]) / csum[(size_t)b*64+np];
          xv = (__expf(vneed-m)/ssum)*cs + 1.f;
        }
        Klt[kd*PAD + s] = f2b(xv);
        kacc += xv;
      }
    } else {
      #pragma unroll
      for (int t=0; t<DKT/2; t++){
        int s = ksrow + t*ksstep;
        float xv = 0.f;
        if (sc0+s < Skv){
          size_t gi = ((size_t)b*Skv + sc0+s)*kstride + h*DKT + kd;
          float kk = KF32 ? ((const float*)Kv)[gi] : b2f(((const u16*)Kv)[gi]);
          xv = ELU ? (kk>0.f? kk+1.f : __expf(kk)) : kk+1.f;
        }
        Klt[kd*PAD + s] = f2b(xv);
        kacc += xv;
      }
    }
    if (DKT==8){  // zero garbage rows 8..15 for the 16-row MFMA tile
      for (int i=tid; i<8*128; i+=256){ int rr=8+(i>>7), s=i&127; Klt[rr*PAD+s]=0; }
    }
    // ---- stage V transposed ----
    #pragma unroll
    for (int t=0; t<16; t++){
      int s = vsrow + t*8;
      u16 raw = 0;
      if (sc0+s < Skv) raw = Vv[((size_t)b*Skv + sc0+s)*256 + h*32 + vv];
      Vlt[vv*PAD + s] = raw;
    }
    __syncthreads();
    // ---- MFMA over this 128-s chunk ----
    #pragma unroll
    for (int kk=0; kk<KPER; kk++){
      int ks = k0w + kk;
      bf16x8 af, bv;
      __builtin_memcpy(&af, &Klt[(mt*16+l15)*PAD + ks*32 + q4*8], 16);
      __builtin_memcpy(&bv, &Vlt[(nt*16+l15)*PAD + ks*32 + q4*8], 16);
      acc = __builtin_amdgcn_mfma_f32_16x16x32_bf16(af, bv, acc, 0,0,0);
    }
    __syncthreads();
  }
  // ---- partial stores ----
  #pragma unroll
  for (int r=0;r<4;r++){
    int row = q4*4 + r;
    if (DKT==32 || row < 8){
      int dg = mt*16 + row;
      atomicAdd(&KV[((size_t)bh*DKT + dg)*32 + nt*16 + l15], acc[r]);
    }
  }
  atomicAdd(&Ksl[kd], kacc);
  __syncthreads();
  if (tid < DKT) atomicAdd(&Ks[(size_t)bh*DKT + tid], Ksl[tid]);
}

// ---------------------------------------------------------------------------
// Small all-fp32 GEMM triple (decoder): g=bx>>7 selects (W,O). mode 0/1(relu).
// amask masks the A row index (proto-broadcast reads without expansion).
// ---------------------------------------------------------------------------
__global__ __launch_bounds__(256) void small_gemm3(
    const float* __restrict__ A,
    const float* __restrict__ W0, const float* __restrict__ W1, const float* __restrict__ W2,
    float* __restrict__ O0, float* __restrict__ O1, float* __restrict__ O2,
    int mode, int amask)
{
  __shared__ float Alds[4][256];
  const int g = blockIdx.x>>7;
  const float* W = g==0?W0:(g==1?W1:W2);
  float* Of = g==0?O0:(g==1?O1:O2);
  const int tid=threadIdx.x; const int r0=(blockIdx.x&127)*4;
  for (int i=tid;i<1024;i+=256){ int r=i>>8, c=i&255;
    Alds[r][c]=A[(size_t)((r0+r)&amask)*256+c]; }
  __syncthreads();
  float a0=0.f,a1=0.f,a2=0.f,a3=0.f;
  for (int k=0;k<256;k++){
    float w=W[(size_t)k*256+tid];
    a0+=Alds[0][k]*w; a1+=Alds[1][k]*w; a2+=Alds[2][k]*w; a3+=Alds[3][k]*w;
  }
  float accs[4]={a0,a1,a2,a3};
  #pragma unroll
  for (int r=0;r<4;r++){
    size_t idx=(size_t)(r0+r)*256+tid; float v=accs[r];
    if (mode==1) v = v>0.f?v:0.f;
    Of[idx]=v;
  }
}

// ---------------------------------------------------------------------------
// Fused decoder chain, 1 row per block (grid 512; 2 blocks/CU). GEMMs are
// K-SPLIT across the 4 waves: wave w covers k in [64w,64w+64) with 4-acc ILP
// and 16-deep W prefetch; partials reduced via 4KB LDS (2 barriers/GEMM).
// KV2 staged early (overlaps dWqm/dWpq GEMMs). Tail Wqp/Wkp dual-split.
// ---------------------------------------------------------------------------
__global__ __launch_bounds__(256) void decoder_chain(
    const float* __restrict__ S1, const float* __restrict__ proq,
    const float* __restrict__ KV1, const float* __restrict__ Ks1,
    const float* __restrict__ KV2, const float* __restrict__ Ks2,
    const float* __restrict__ dWqm, const float* __restrict__ dl1g, const float* __restrict__ dl1b,
    const float* __restrict__ dWpq,
    const float* __restrict__ dWpm, const float* __restrict__ dl2g, const float* __restrict__ dl2b,
    const float* __restrict__ dWf1, const float* __restrict__ dWf2,
    const float* __restrict__ dl3g, const float* __restrict__ dl3b,
    const float* __restrict__ Wqp, const float* __restrict__ Wkp,
    float* __restrict__ ppf, float* __restrict__ pkf)
{
  __shared__ float KVl[8*32*32];     // 32 KB
  __shared__ float Ksl[8*32];
  __shared__ float rowA[256];
  __shared__ float rowB[256];
  __shared__ float red[4], red2[4];
  __shared__ float gred[4][256];     // k-split partials
  const int tid = threadIdx.x;
  const int r0g = blockIdx.x;        // one row per block
  const int b = r0g >> 6;
  const int h = tid>>5, vv = tid&31;
  const int w_ = tid>>6, ln_ = tid&63;

  // k-split GEMM: wave w_ covers k in [64w_,64w_+64); 4 accumulators; 16-deep
  // double-buffered W prefetch; LDS 4-way reduce.
  auto gemmS = [&](const float* Ain, const float* __restrict__ W, float& out){
    const int kb = w_*64;
    float a0=0.f,a1=0.f,a2=0.f,a3=0.f;
    float wv[16], wn[16];
    #pragma unroll
    for (int u=0;u<16;u++) wn[u]=0.f;
    #pragma unroll
    for (int u=0;u<16;u++) wv[u]=W[(size_t)(kb+u)*256+tid];
    #pragma unroll
    for (int kc=0;kc<64;kc+=16){
      if (kc<48){
        #pragma unroll
        for (int u=0;u<16;u++) wn[u]=W[(size_t)(kb+kc+16+u)*256+tid];
      }
      #pragma unroll
      for (int u=0;u<16;u+=4){
        a0+=Ain[kb+kc+u  ]*wv[u  ];
        a1+=Ain[kb+kc+u+1]*wv[u+1];
        a2+=Ain[kb+kc+u+2]*wv[u+2];
        a3+=Ain[kb+kc+u+3]*wv[u+3];
      }
      #pragma unroll
      for (int u=0;u<16;u++) wv[u]=wn[u];
    }
    gred[w_][tid]=(a0+a1)+(a2+a3);
    __syncthreads();
    out = (gred[0][tid]+gred[1][tid])+(gred[2][tid]+gred[3][tid]);
    __syncthreads();
  };
  // dual-output k-split GEMM (tail projections), 8-deep prefetch per stream.
  auto gemmS2 = [&](const float* Ain, const float* __restrict__ Wa,
                    const float* __restrict__ Wb, float& oa, float& ob){
    const int kb = w_*64;
    float a0=0.f,a1=0.f,b0=0.f,b1=0.f;
    float wa[8], wb[8], na[8], nb[8];
    #pragma unroll
    for (int u=0;u<8;u++){ na[u]=0.f; nb[u]=0.f; }
    #pragma unroll
    for (int u=0;u<8;u++){ wa[u]=Wa[(size_t)(kb+u)*256+tid]; wb[u]=Wb[(size_t)(kb+u)*256+tid]; }
    #pragma unroll
    for (int kc=0;kc<64;kc+=8){
      if (kc<56){
        #pragma unroll
        for (int u=0;u<8;u++){ na[u]=Wa[(size_t)(kb+kc+8+u)*256+tid]; nb[u]=Wb[(size_t)(kb+kc+8+u)*256+tid]; }
      }
      #pragma unroll
      for (int u=0;u<8;u+=2){
        float av0=Ain[kb+kc+u], av1=Ain[kb+kc+u+1];
        a0+=av0*wa[u]; a1+=av1*wa[u+1];
        b0+=av0*wb[u]; b1+=av1*wb[u+1];
      }
      #pragma unroll
      for (int u=0;u<8;u++){ wa[u]=na[u]; wb[u]=nb[u]; }
    }
    gred[w_][tid]=a0+a1;
    __syncthreads();
    oa = (gred[0][tid]+gred[1][tid])+(gred[2][tid]+gred[3][tid]);
    __syncthreads();
    gred[w_][tid]=b0+b1;
    __syncthreads();
    ob = (gred[0][tid]+gred[1][tid])+(gred[2][tid]+gred[3][tid]);
    __syncthreads();
  };
  // exact two-pass LN over 256 cols; trailing sync so Out is readable after.
  auto lnS = [&](float v, const float* __restrict__ g, const float* __restrict__ be,
                 float* Out){
    float s=v;
    #pragma unroll
    for (int off=32;off;off>>=1) s+=__shfl_xor(s,off);
    if (ln_==0) red[w_]=s;
    __syncthreads();
    float mean=(red[0]+red[1]+red[2]+red[3])*(1.f/256.f);
    float d=v-mean; float q=d*d;
    #pragma unroll
    for (int off=32;off;off>>=1) q+=__shfl_xor(q,off);
    if (ln_==0) red2[w_]=q;
    __syncthreads();
    float var=(red2[0]+red2[1]+red2[2]+red2[3])*(1.f/256.f);
    Out[tid]=d*rsqrtf(var+1e-5f)*g[tid]+be[tid];
    __syncthreads();
  };
  // linear-attention apply (DKT=32, ELU). In-place safe (sync before write).
  auto applyS = [&](float* Q, float* Out){
    float z=0.f,o=0.f;
    #pragma unroll 8
    for (int d=0;d<32;d++){
      float q = Q[h*32+d];
      q = q>0.f? q+1.f : __expf(q);
      z += q*Ksl[h*32+d];
      o += q*KVl[(h*32+d)*32+vv];
    }
    float res=o/(z+1e-6f);
    __syncthreads();                 // all reads of Q + KVl done before overwrite
    Out[h*32+vv]=res;
    __syncthreads();
  };

  // stage: q row + KV1
  for (int i=tid;i<8192;i+=256) KVl[i]=KV1[(size_t)b*8192+i];
  Ksl[tid]=Ks1[(size_t)b*256+tid];
  rowA[tid]=S1[(size_t)r0g*256+tid];
  __syncthreads();
  applyS(rowA,rowB);                                   // msg_attn; KVl free after
  // stage KV2 NOW -- overlaps the next two GEMMs + LN (barrier before next apply)
  for (int i=tid;i<8192;i+=256) KVl[i]=KV2[(size_t)b*8192+i];
  Ksl[tid]=Ks2[(size_t)b*256+tid];
  float v, v2;
  gemmS(rowB,dWqm,v);
  v += proq[(size_t)(r0g&63)*256+tid];
  lnS(v,dl1g,dl1b,rowA);                               // rowA = msg
  gemmS(rowA,dWpq,v2);                                 // mq row
  rowB[tid]=v2;
  __syncthreads();                                     // KV2 staging + rowB visible
  applyS(rowB,rowB);                                   // proto_attn (in place)
  gemmS(rowB,dWpm,v);
  v += rowA[tid];                                      // + msg residual
  lnS(v,dl2g,dl2b,rowA);                               // rowA = proto
  gemmS(rowA,dWf1,v);
  rowB[tid]=v>0.f?v:0.f;
  __syncthreads();
  gemmS(rowB,dWf2,v);
  v += rowA[tid];                                      // + proto residual
  lnS(v,dl3g,dl3b,rowA);                               // rowA = decoder out
  gemmS2(rowA,Wqp,Wkp,v,v2);
  ppf[(size_t)r0g*256+tid]=v;
  pkf[(size_t)r0g*256+tid]=v2;
}

// ---------------------------------------------------------------------------
// Per-batch M[c,np] = sum_j W[c,j]*P[b*64+np,j] -> TRANSPOSED hi/lo bf16.
// Dual: blockIdx.z selects (W,P,out) set. grid(8,16,2).
// ---------------------------------------------------------------------------
__global__ __launch_bounds__(256) void proj_mat2(
    const float* __restrict__ Wa, const float* __restrict__ Pa,
    u16* __restrict__ Mha, u16* __restrict__ Mla,
    const float* __restrict__ Wb, const float* __restrict__ Pb,
    u16* __restrict__ Mhb, u16* __restrict__ Mlb)
{
  __shared__ float PL[64][256];
  const float* W = blockIdx.z? Wb:Wa;
  const float* P = blockIdx.z? Pb:Pa;
  u16* MhT = blockIdx.z? Mhb:Mha;
  u16* MlT = blockIdx.z? Mlb:Mla;
  const int b = blockIdx.x, c0 = blockIdx.y*16, tid = threadIdx.x;
  for (int i=tid;i<16384;i+=256){ int row=i>>8, col=i&255;
    PL[row][col] = P[(size_t)(b*64+row)*256 + col]; }
  __syncthreads();
  const int np = tid&63, cl = tid>>6;
  #pragma unroll
  for (int rr=0;rr<4;rr++){
    int ci = cl + rr*4;
    float acc=0.f;
    for (int j=0;j<256;j++) acc += W[(size_t)(c0+ci)*256+j]*PL[np][j];
    size_t idx = (size_t)b*16384 + (size_t)np*256 + (c0+ci);
    u16 h=f2b(acc); MhT[idx]=h; MlT[idx]=f2b(acc-b2f(h));
  }
}

// ---------------------------------------------------------------------------
// Old scalar KV reduce (decoder only, fp32 in, S=64).
// ---------------------------------------------------------------------------
template<int DKT, bool ELU>
__global__ __launch_bounds__(256) void la_reduce(
    const float* __restrict__ Kv, int kstride, const float* __restrict__ Vv,
    float* __restrict__ KV, float* __restrict__ Ks, int Skv, int clen)
{
  __shared__ float Kl[64*DKT];
  __shared__ float Vl[64*32];
  const int b = blockIdx.y>>3, h = blockIdx.y&7;
  const int tid=threadIdx.x;
  const int s0 = blockIdx.x*clen; const int s1 = imin(s0+clen, Skv);
  const int d0 = tid>>5, vvv = tid&31;
  float acc[DKT/8], kac[DKT/8];
  #pragma unroll
  for (int p=0;p<DKT/8;p++){ acc[p]=0.f; kac[p]=0.f; }
  for (int sc=s0; sc<s1; sc+=64){
    int ns = imin(64, s1-sc);
    for (int i=tid;i<ns*DKT;i+=256){ int s=i/DKT, d=i-s*DKT;
      float xv = Kv[((size_t)b*Skv + sc+s)*kstride + h*DKT + d];
      Kl[s*DKT+d] = ELU ? (xv>0.f? xv+1.f : __expf(xv)) : xv+1.f; }
    for (int i=tid;i<ns*32;i+=256){ int s=i>>5, c=i&31;
      Vl[s*32+c] = Vv[((size_t)b*Skv+sc+s)*256 + h*32 + c]; }
    __syncthreads();
    for (int s=0;s<ns;s++){
      float vval = Vl[s*32+vvv];
      #pragma unroll
      for (int p=0;p<DKT/8;p++){ float kk=Kl[s*DKT + d0+8*p]; acc[p]+=kk*vval; kac[p]+=kk; }
    }
    __syncthreads();
  }
  #pragma unroll
  for (int p=0;p<DKT/8;p++)
    atomicAdd(&KV[(((size_t)b*8+h)*DKT + d0+8*p)*32 + vvv], acc[p]);
  if (vvv==0){
    #pragma unroll
    for (int p=0;p<DKT/8;p++)
      atomicAdd(&Ks[((size_t)b*8+h)*DKT + d0+8*p], kac[p]);
  }
}

// ---------------------------------------------------------------------------
// Apply: out[l,h*32+v]=(sum_d Q'[d]*KV[d,v])/(sum_d Q'[d]*Ks[d]+1e-6)
// QSM (DKT=8): Q' computed inline from raw logits.
// ---------------------------------------------------------------------------
template<int DKT, bool ELU, bool OUTBF, bool QSM>
__global__ __launch_bounds__(256) void la_apply(
    const float* __restrict__ Qsrc, const float* __restrict__ KV,
    const float* __restrict__ Ks, int Lq, float* __restrict__ outf, u16* __restrict__ outb,
    const float* __restrict__ cmax, const float* __restrict__ csum)
{
  __shared__ float KVl[8*DKT*32];
  __shared__ float Ksl[8*DKT];
  __shared__ float Ql[16*8*DKT];
  const int b = blockIdx.y; const int r0 = blockIdx.x*16;
  const int tid = threadIdx.x;
  const float* KVb = KV + (size_t)b*8*DKT*32;
  for (int i=tid;i<8*DKT*32;i+=256) KVl[i]=KVb[i];
  for (int i=tid;i<8*DKT;i+=256) Ksl[i]=Ks[(size_t)b*8*DKT + i];
  if constexpr (QSM){
    const int wv = tid>>6, ln = tid&63;
    #pragma unroll
    for (int rr=0;rr<4;rr++){
      const int r = wv*4+rr;
      float v = Qsrc[((size_t)b*Lq + r0 + r)*64 + ln];
      float m = v;
      #pragma unroll
      for (int off=32;off;off>>=1) m = fmaxf(m, __shfl_xor(m,off));
      float e = __expf(v-m);
      float s = e;
      #pragma unroll
      for (int off=32;off;off>>=1) s += __shfl_xor(s,off);
      float cs = __expf(v - cmax[(size_t)b*64+ln]) / csum[(size_t)b*64+ln];
      Ql[r*64+ln] = (e/s)*cs;
    }
  } else {
    for (int i=tid;i<16*8*DKT;i+=256){ int r=i/(8*DKT); int c=i-r*(8*DKT);
        Ql[i] = Qsrc[((size_t)b*Lq + r0 + r)*(8*DKT) + c]; }
  }
  __syncthreads();
  const int h = tid>>5, vv = tid&31;
  for (int r=0;r<16;r++){
    float z=0.f, o=0.f;
    #pragma unroll
    for (int d=0; d<DKT; d++){
      float q = Ql[r*8*DKT + h*DKT + d];
      q = ELU ? (q>0.f? q+1.f : __expf(q)) : q+1.f;
      z += q*Ksl[h*DKT+d];
      o += q*KVl[(h*DKT+d)*32 + vv];
    }
    float res = o/(z+1e-6f);
    size_t idx = ((size_t)b*Lq + r0+r)*256 + h*32+vv;
    if (OUTBF) outb[idx]=f2b(res); else outf[idx]=res;
  }
}

// ---------------------------------------------------------------------------
// LayerNorm over 256, eps=1e-5 — wave-per-row, vectorized, no LDS/barriers.
// MODE 1: bf16 LN(A)->Ob in-place; MODE 2: fp32 xadd + LN(A)->Ox, A bf16 if ABF.
// Grid = rows/4.
// ---------------------------------------------------------------------------
template<int MODE, bool ABF>
__global__ __launch_bounds__(256) void ln_kernel(
  const void* __restrict__ Av, const float* __restrict__ resid,
  const float* __restrict__ g, const float* __restrict__ be,
  float* __restrict__ Of, u16* __restrict__ Ob, const float* __restrict__ xadd,
  float* __restrict__ Ox)
{
  const int tid = threadIdx.x;
  const size_t row = (size_t)blockIdx.x*4 + (tid>>6);
  const int lane = tid&63;
  const int c0 = lane<<2;
  const size_t gi = row*256 + c0;
  float v[4];
  if (MODE==1 || ABF){
    ushort4 u = *(const ushort4*)((const u16*)Av + gi);
    v[0]=b2f(u.x); v[1]=b2f(u.y); v[2]=b2f(u.z); v[3]=b2f(u.w);
  } else {
    float4 f = *(const float4*)((const float*)Av + gi);
    v[0]=f.x; v[1]=f.y; v[2]=f.z; v[3]=f.w;
  }
  if (MODE==0){
    float4 r = *(const float4*)(resid + gi);
    v[0]+=r.x; v[1]+=r.y; v[2]+=r.z; v[3]+=r.w;
  }
  float s = v[0]+v[1]+v[2]+v[3];
  #pragma unroll
  for (int off=32;off;off>>=1) s += __shfl_xor(s,off);
  const float mean = s*(1.f/256.f);
  float d[4]; float qq=0.f;
  #pragma unroll
  for (int i=0;i<4;i++){ d[i]=v[i]-mean; qq += d[i]*d[i]; }
  #pragma unroll
  for (int off=32;off;off>>=1) qq += __shfl_xor(qq,off);
  const float rstd = rsqrtf(qq*(1.f/256.f)+1e-5f);
  const float4 gv = *(const float4*)(g+c0);
  const float4 bv = *(const float4*)(be+c0);
  float y[4];
  y[0]=d[0]*rstd*gv.x+bv.x; y[1]=d[1]*rstd*gv.y+bv.y;
  y[2]=d[2]*rstd*gv.z+bv.z; y[3]=d[3]*rstd*gv.w+bv.w;
  if (MODE==0){
    *(float4*)(Of+gi) = make_float4(y[0],y[1],y[2],y[3]);
  } else if (MODE==1){
    ushort4 o; o.x=f2b(y[0]); o.y=f2b(y[1]); o.z=f2b(y[2]); o.w=f2b(y[3]);
    *(ushort4*)(Ob+gi)=o;
  } else {
    const float4 xa = *(const float4*)(xadd+gi);
    *(float4*)(Ox+gi) = make_float4(xa.x+y[0], xa.y+y[1], xa.z+y[2], xa.w+y[3]);
  }
}

// ---------------------------------------------------------------------------
// Column softmax stats over axis=1 (4800 rows/batch), dual: grid(64, NB, 2).
// ---------------------------------------------------------------------------
__global__ __launch_bounds__(256) void col_stats(
    const float* __restrict__ logits0, float* __restrict__ cmax0, float* __restrict__ csum0,
    const float* __restrict__ logits1, float* __restrict__ cmax1, float* __restrict__ csum1)
{
  int np = blockIdx.x, b = blockIdx.y;
  const float* logits = blockIdx.z? logits1:logits0;
  float* cmax = blockIdx.z? cmax1:cmax0;
  float* csum = blockIdx.z? csum1:csum0;
  const float* base = logits + ((size_t)b*4800)*64 + np;
  int tid = threadIdx.x;
  float vloc[19];
  float m = -3.0e38f;
  #pragma unroll
  for (int i=0;i<19;i++){ int l = tid + i*256;
    float v = (l<4800)? base[(size_t)l*64] : -3.0e38f;
    vloc[i]=v; m = fmaxf(m,v); }
  #pragma unroll
  for (int off=32;off;off>>=1) m = fmaxf(m, __shfl_xor(m,off));
  __shared__ float red[4], red2[4];
  int w = tid>>6, ln = tid&63;
  if (ln==0) red[w]=m;
  __syncthreads();
  m = fmaxf(fmaxf(red[0],red[1]), fmaxf(red[2],red[3]));
  float s=0.f;
  #pragma unroll
  for (int i=0;i<19;i++){ int l = tid + i*256; if (l<4800) s += __expf(vloc[i]-m); }
  #pragma unroll
  for (int off=32;off;off>>=1) s += __shfl_xor(s,off);
  if (ln==0) red2[w]=s;
  __syncthreads();
  s = red2[0]+red2[1]+red2[2]+red2[3];
  if (tid==0){ cmax[b*64+np]=m; csum[b*64+np]=s; }
}

// ---------------------------------------------------------------------------
extern "C" void kernel_launch(void* const* d_in, const int* in_sizes, int n_in,
                              void* d_out, int out_size, void* d_ws, size_t ws_size,
                              hipStream_t stream) {
  (void)in_sizes; (void)n_in; (void)out_size; (void)ws_size;
  const float* x    = (const float*)d_in[0];
  const float* srcp = (const float*)d_in[1];
  const float* Wq   = (const float*)d_in[4];
  const float* Wk   = (const float*)d_in[5];
  const float* Wv   = (const float*)d_in[6];
  const float* Wqp  = (const float*)d_in[7];
  const float* Wkp  = (const float*)d_in[8];
  const float* Wmg  = (const float*)d_in[9];
  const float* Wm1  = (const float*)d_in[10];
  const float* Wm2  = (const float*)d_in[11];
  const float* ln1g = (const float*)d_in[12];
  const float* ln1b = (const float*)d_in[13];
  const float* ln2g = (const float*)d_in[14];
  const float* ln2b = (const float*)d_in[15];
  const float* proq = (const float*)d_in[16];
  const float* dWqq = (const float*)d_in[17];
  const float* dWqk = (const float*)d_in[18];
  const float* dWqv = (const float*)d_in[19];
  const float* dWqm = (const float*)d_in[20];
  const float* dl1g = (const float*)d_in[21];
  const float* dl1b = (const float*)d_in[22];
  const float* dWpq = (const float*)d_in[23];
  const float* dWpk = (const float*)d_in[24];
  const float* dWpv = (const float*)d_in[25];
  const float* dWpm = (const float*)d_in[26];
  const float* dWf1 = (const float*)d_in[29];
  const float* dWf2 = (const float*)d_in[30];
  const float* dl3g = (const float*)d_in[31];
  const float* dl3b = (const float*)d_in[32];
  const float* dl2g = (const float*)d_in[27];
  const float* dl2b = (const float*)d_in[28];

  char* p=(char*)d_ws;
  auto alloc=[&](size_t n)->char*{ char* r=p; p+=((n+255)&~(size_t)255); return r; };
  u16* xb  = (u16*)alloc(19660800);   // x bf16 hi
  u16* xlo = (u16*)alloc(19660800);   // x bf16 lo residual
  u16* sb  = (u16*)alloc(19660800);   // source bf16 hi
  u16* slo = (u16*)alloc(19660800);   // source bf16 lo
  u16* bufA= (u16*)alloc(19660800);   // fk
  u16* bufB= (u16*)alloc(19660800);   // fv -> msg0b
  u16* v0b = (u16*)alloc(19660800);   // v0 (computed in TRI launch)
  u16* msg1b=(u16*)alloc(19660800);   // merge out bf16
  u16* h1  = (u16*)alloc(39321600);   // MLP hidden bf16 [38400,512]
  u16* mlp2b=(u16*)alloc(19660800);   // MLP out bf16
  float* qsm=(float*)alloc(9830400);  // q logits fp32 [38400,64]
  float* ksm=(float*)alloc(9830400);  // k logits fp32 [38400,64]
  u16* dWpkT=(u16*)alloc(131072); u16* dWpvT=(u16*)alloc(131072);
  u16* WvT  =(u16*)alloc(131072); u16* WmgT =(u16*)alloc(131072);
  u16* Wm1T =(u16*)alloc(524288); u16* Wm2T =(u16*)alloc(262144);
  float* S0=(float*)alloc(524288); float* S1=(float*)alloc(524288);
  float* S2=(float*)alloc(524288); float* S3=(float*)alloc(524288);
  float* S4=(float*)alloc(524288); float* S5=(float*)alloc(524288);
  float* ppf=(float*)alloc(524288); float* pkf=(float*)alloc(524288);
  u16* Mqh=(u16*)alloc(262144); u16* Mql=(u16*)alloc(262144);
  u16* Mkh=(u16*)alloc(262144); u16* Mkl=(u16*)alloc(262144);
  char* z0=p;
  float* KV1=(float*)alloc(262144); float* Ks1=(float*)alloc(8192);
  float* KV2=(float*)alloc(262144); float* Ks2=(float*)alloc(8192);
  float* KVm=(float*)alloc(65536);  float* Ksm=(float*)alloc(2048);
  char* z1=p;
  float* cmq=(float*)alloc(2048); float* csq=(float*)alloc(2048);
  float* cmk=(float*)alloc(2048); float* csk=(float*)alloc(2048);
  (void)S4; (void)S5;

  u16* fk=bufA;
  u16* fv=bufB; u16* msg0b=bufB;
  float* dof=(float*)d_out;

  hipMemsetAsync(z0, 0, (size_t)(z1-z0), stream);

  dim3 blk(256);
  // ---- phase 0: splits + weight transposes ----
  cvt_split2<<<dim3(19200),blk,0,stream>>>(x, xb, xlo, srcp, sb, slo, 9830400);
  wtrans4<<<dim3(256,4),blk,0,stream>>>(dWpk,dWpv,Wv,Wmg, dWpkT,dWpvT,WvT,WmgT);
  wtrans2<<<dim3(1536),blk,0,stream>>>(Wm1, Wm1T, Wm2, Wm2T);
  // ---- phase 1: fk, fv AND v0 in one TRI launch, then MFMA KV reduce ----
  gemm128<256,1,false,3><<<dim3(300,2,3),blk,0,stream>>>(
      xb,nullptr,sb, dWpkT,dWpvT,WvT, nullptr, fk,fv,v0b, 256,0);
  la_reduce_mfma<32,true,false,false><<<dim3(19,64),blk,0,stream>>>(
      fk,256,fv,KV2,Ks2,4800,nullptr,nullptr);
  // ---- phase 2: DETR decoder, fully fused; warm chain weights into every
  //      XCD L2 right before the chain ----
  small_gemm3<<<dim3(384),blk,0,stream>>>(proq,dWqq,dWqk,dWqv,S1,S2,S3,0,63);
  la_reduce<32,true><<<dim3(1,64),blk,0,stream>>>(S2,256,S3,KV1,Ks1,64,64);
  warm7<<<dim3(3584),blk,0,stream>>>(dWqm,dWpq,dWpm,dWf1,dWf2,Wqp,Wkp,S0);
  decoder_chain<<<dim3(512),blk,0,stream>>>(
      S1,proq, KV1,Ks1, KV2,Ks2,
      dWqm,dl1g,dl1b, dWpq, dWpm,dl2g,dl2b, dWf1,dWf2,dl3g,dl3b,
      Wqp,Wkp, ppf,pkf);
  // ---- phase 3: folded reprojection matrices (dual, one launch) ----
  proj_mat2<<<dim3(8,16,2),blk,0,stream>>>(Wq,ppf,Mqh,Mql, Wk,pkf,Mkh,Mkl);
  // ---- phase 4: logits (dual) + col stats (dual); row softmax fused into
  //      consumers (la_apply / la_reduce_mfma) ----
  gemm_logits2<<<dim3(600,2),blk,0,stream>>>(xb,xlo,Mqh,Mql,qsm, sb,slo,Mkh,Mkl,ksm);
  col_stats<<<dim3(64,8,2),blk,0,stream>>>(qsm,cmq,csq, ksm,cmk,csk);
  // ---- phase 5: main MFMA KV reduce (k-softmax inline; v0 from phase 1) ----
  la_reduce_mfma<8,false,true,true><<<dim3(19,64),blk,0,stream>>>(
      ksm,64,v0b,KVm,Ksm,4800,cmk,csk);
  // ---- phase 6: apply (q-softmax inline) + merge + LN1 ----
  la_apply<8,false,true,true><<<dim3(300,8),blk,0,stream>>>(
      qsm,KVm,Ksm,4800,nullptr,msg0b,cmq,csq);
  gemm128<256,1,false,1><<<dim3(300,2),blk,0,stream>>>(
      msg0b,nullptr,nullptr, WmgT,nullptr,nullptr, nullptr, msg1b,nullptr,nullptr, 256,0);
  ln_kernel<1,false><<<dim3(9600),blk,0,stream>>>(msg1b,nullptr,ln1g,ln1b,nullptr,msg1b,nullptr,nullptr);
  // ---- phase 7: MLP (cat inside) + LN2 + residual ----
  gemm128<512,2,true,1><<<dim3(300,4),blk,0,stream>>>(
      xb,msg1b,nullptr, Wm1T,nullptr,nullptr, nullptr, h1,nullptr,nullptr, 512,0);
  gemm128<512,1,false,1><<<dim3(300,2),blk,0,stream>>>(
      h1,nullptr,nullptr, Wm2T,nullptr,nullptr, nullptr, mlp2b,nullptr,nullptr, 256,0);
  ln_kernel<2,true><<<dim3(9600),blk,0,stream>>>(mlp2b,nullptr,ln2g,ln2b,nullptr,nullptr,x,dof);
}

// Round 13
// 521.427 us; speedup vs baseline: 1.1223x; 1.1223x over previous
//
#include <hip/hip_runtime.h>
#include <hip/hip_bf16.h>

typedef unsigned short u16;
typedef __bf16 bf16x8 __attribute__((ext_vector_type(8)));
typedef float  f32x4  __attribute__((ext_vector_type(4)));

__device__ __forceinline__ float b2f(u16 u){
  union{ unsigned int i; float f; } a; a.i = ((unsigned int)u)<<16; return a.f;
}
__device__ __forceinline__ u16 f2b(float f){
  __hip_bfloat16 h = __float2bfloat16(f);
  u16 r; __builtin_memcpy(&r, &h, 2); return r;
}
__device__ __forceinline__ int imin(int a,int b){ return a<b?a:b; }

// async global->LDS, 16B per lane: HW writes ldsbase + lane*16.
__device__ __forceinline__ void gl_lds16(const void* g, void* l){
  __builtin_amdgcn_global_load_lds(
      (const __attribute__((address_space(1))) void*)g,
      (__attribute__((address_space(3))) void*)l, 16, 0, 0);
}
__device__ __forceinline__ void vm_drain(){
  asm volatile("s_waitcnt vmcnt(0)" ::: "memory");
}
__device__ __forceinline__ void vm_wait4(){
  asm volatile("s_waitcnt vmcnt(4)" ::: "memory");
}

// ---------------------------------------------------------------------------
// 128x128 MFMA GEMM: C[M,N] = A[M,K]bf16 @ Wt[N,K]bf16^T.
// OUTMODE: 0 fp32, 1 bf16, 2 bf16+relu. CAT: k<256 A, k>=256 A2 (stride 256).
// NSEL: up to 3 independent GEMMs in one launch; bz selects (A,W,out).
// XCD remap for A-tile L2 reuse (NB divisible by 8 at all call sites).
// LDS XOR swizzle (src pre-swizzled, read XOR). Triple-buffer + vmcnt(4).
// ---------------------------------------------------------------------------
template<int KD, int OUTMODE, bool CAT, int NSEL>
__global__ __launch_bounds__(256) void gemm128(
    const u16* __restrict__ A, const u16* __restrict__ A2, const u16* __restrict__ A3,
    const u16* __restrict__ Wt, const u16* __restrict__ Wt2, const u16* __restrict__ Wt3,
    float* __restrict__ Cf, u16* __restrict__ Cb, u16* __restrict__ Cb2, u16* __restrict__ Cb3,
    int NDIM, int aoff)
{
  __shared__ u16 At[3][128*32];
  __shared__ u16 Bt[3][128*32];
  const int tid = threadIdx.x;
  const int ny = gridDim.y, nz = gridDim.z;
  const int NB = gridDim.x*ny*nz;
  const int L  = blockIdx.x + gridDim.x*(blockIdx.y + ny*blockIdx.z);
  const int cpx = NB >> 3;
  const int wkid = (L & 7)*cpx + (L >> 3);
  const int nc = ny*nz;
  const int bx = wkid / nc;
  const int cc_ = wkid - bx*nc;
  const int by = cc_ % ny;
  const int bz = cc_ / ny;

  const u16* Aa = (NSEL>=3 && bz==2) ? A3 : A;
  const u16* W  = (NSEL>=2 && bz==1) ? Wt2 : ((NSEL>=3 && bz==2) ? Wt3 : Wt);
  u16* Cbo      = (NSEL>=2 && bz==1) ? Cb2 : ((NSEL>=3 && bz==2) ? Cb3 : Cb);
  const int w = tid>>6, lane = tid&63;
  const int q4 = lane>>4, l15 = lane&15;
  const int wr = w>>1, wc = w&1;
  const int rstage = lane>>2;
  const int kcol = (((lane&3) ^ ((lane>>2)&3))<<3);
  const size_t arow0 = (size_t)(aoff + bx*128);
  const int n0 = by*128;

  f32x4 acc[4][4];
  #pragma unroll
  for (int i=0;i<4;i++)
    #pragma unroll
    for (int j=0;j<4;j++){ acc[i][j][0]=0.f; acc[i][j][1]=0.f; acc[i][j][2]=0.f; acc[i][j][3]=0.f; }

  auto stage = [&](int k0, int buf){
    #pragma unroll
    for (int j=0;j<2;j++){
      const int trow = w*32 + j*16 + rstage;
      const u16* ga;
      if (CAT){
        ga = (k0<256) ? (A  + (arow0+trow)*256 + k0 + kcol)
                      : (A2 + (arow0+trow)*256 + (k0-256) + kcol);
      } else {
        ga = Aa + (arow0+trow)*(size_t)KD + k0 + kcol;
      }
      gl_lds16(ga, &At[buf][(w*32+j*16)*32]);
      const u16* gb = W + (size_t)(n0 + trow)*KD + k0 + kcol;
      gl_lds16(gb, &Bt[buf][(w*32+j*16)*32]);
    }
  };

  constexpr int NK = KD/32;            // >= 8 for all instantiations
  stage(0, 0);
  stage(32, 1);
  vm_wait4();                          // tile 0 landed; tile 1 in flight
  __builtin_amdgcn_s_barrier();
  int cb = 0;                          // compute-buffer index (t % 3)
  for (int t=0; t<NK; ++t){
    if (t+2 < NK){
      int sbuf = cb ? cb-1 : 2;        // (t+2) % 3
      stage((t+2)*32, sbuf);
    }
    bf16x8 af[4], bv[4];
    #pragma unroll
    for (int i=0;i<4;i++){
      __builtin_memcpy(&af[i], &At[cb][(wr*64 + i*16 + l15)*32 + ((q4^(l15&3))<<3)], 16);
      __builtin_memcpy(&bv[i], &Bt[cb][(wc*64 + i*16 + l15)*32 + ((q4^(l15&3))<<3)], 16);
    }
    #pragma unroll
    for (int i=0;i<4;i++)
      #pragma unroll
      for (int j=0;j<4;j++)
        acc[i][j] = __builtin_amdgcn_mfma_f32_16x16x32_bf16(af[i], bv[j], acc[i][j], 0,0,0);
    if (t+1 < NK){
      if (t+2 < NK) vm_wait4(); else vm_drain();
      __builtin_amdgcn_s_barrier();
      cb = (cb==2)? 0 : cb+1;
    }
  }
  #pragma unroll
  for (int i=0;i<4;i++){
    const int row0 = bx*128 + wr*64 + i*16 + q4*4;
    #pragma unroll
    for (int j=0;j<4;j++){
      const int col = n0 + wc*64 + j*16 + l15;
      #pragma unroll
      for (int r=0;r<4;r++){
        float v = acc[i][j][r];
        size_t idx = (size_t)(row0+r)*NDIM + col;
        if (OUTMODE==0) Cf[idx]=v;
        else if (OUTMODE==1) Cbo[idx]=f2b(v);
        else Cbo[idx]=f2b(v>0.f?v:0.f);
      }
    }
  }
}

// fp32 -> bf16 hi + lo residual, two tensors in one launch (grid 2*n/1024)
__global__ __launch_bounds__(256) void cvt_split2(
    const float* __restrict__ inA, u16* __restrict__ ohA, u16* __restrict__ olA,
    const float* __restrict__ inB, u16* __restrict__ ohB, u16* __restrict__ olB, int n){
  int i = (blockIdx.x*256 + threadIdx.x)*4;
  const float* in; u16 *oh, *ol; int j;
  if (i < n){ in=inA; oh=ohA; ol=olA; j=i; }
  else      { in=inB; oh=ohB; ol=olB; j=i-n; }
  float4 f = *(const float4*)(in+j);
  float v[4]={f.x,f.y,f.z,f.w};
  #pragma unroll
  for (int t=0;t<4;t++){ u16 h=f2b(v[t]); oh[j+t]=h; ol[j+t]=f2b(v[t]-b2f(h)); }
}

// four 256x256 transposes in one launch, grid (256,4)
__global__ __launch_bounds__(256) void wtrans4(
    const float* __restrict__ W0, const float* __restrict__ W1,
    const float* __restrict__ W2, const float* __restrict__ W3,
    u16* __restrict__ T0, u16* __restrict__ T1,
    u16* __restrict__ T2, u16* __restrict__ T3)
{
  const int g = blockIdx.y;
  const float* W = g==0?W0:(g==1?W1:(g==2?W2:W3));
  u16* T = g==0?T0:(g==1?T1:(g==2?T2:T3));
  int idx = blockIdx.x*256 + threadIdx.x;
  int nn = idx>>8, kk = idx&255;
  T[idx] = f2b(W[(size_t)kk*256 + nn]);
}

// Wm1 [512,512] and Wm2 [512,256] transposes in one launch, grid 1536
__global__ __launch_bounds__(256) void wtrans2(
    const float* __restrict__ W1, u16* __restrict__ T1,
    const float* __restrict__ W2, u16* __restrict__ T2)
{
  int idx = blockIdx.x*256 + threadIdx.x;
  if (idx < 512*512){
    int nn = idx>>9, kk = idx&511;
    T1[idx] = f2b(W1[(size_t)kk*512 + nn]);
  } else {
    int j = idx - 512*512;           // 0..131071, N=256 K=512
    int nn = j>>9, kk = j&511;
    T2[j] = f2b(W2[(size_t)kk*256 + nn]);
  }
}

// ---------------------------------------------------------------------------
// L2 warm for the decoder chain weights: 8 consecutive blocks read the SAME
// 1KB-per-thread slice (one block per XCD by round-robin dispatch), pulling a
// full copy of all 7 weights into every XCD's private L2. grid 3584.
// ---------------------------------------------------------------------------
__global__ __launch_bounds__(256) void warm7(
    const float* __restrict__ W0, const float* __restrict__ W1,
    const float* __restrict__ W2, const float* __restrict__ W3,
    const float* __restrict__ W4, const float* __restrict__ W5,
    const float* __restrict__ W6, float* __restrict__ scratch)
{
  const int slice = blockIdx.x >> 3;            // 0..447
  const int wsel = slice >> 6;                  // weight 0..6
  const int off = ((slice & 63)<<8) + threadIdx.x;  // float4 index
  const float* W = wsel==0?W0:wsel==1?W1:wsel==2?W2:wsel==3?W3:wsel==4?W4:wsel==5?W5:W6;
  float4 v = ((const float4*)W)[off];
  float s = v.x+v.y+v.z+v.w;
  if (s == 1234567.891f) scratch[blockIdx.x] = s;   // keeps loads live, never taken
}

// ---------------------------------------------------------------------------
// Logits GEMM v2 (dual): Out[l,np] = A[l,:].M[:,np] via hi/lo bf16 (hh+hl+lh).
// blockIdx.y selects the (A,B,Out) set (q vs k). Triple-buffer counted-vmcnt.
// ---------------------------------------------------------------------------
__global__ __launch_bounds__(256) void gemm_logits2(
    const u16* __restrict__ Ah0, const u16* __restrict__ Al0,
    const u16* __restrict__ Bh0, const u16* __restrict__ Bl0,
    float* __restrict__ O0,
    const u16* __restrict__ Ah1, const u16* __restrict__ Al1,
    const u16* __restrict__ Bh1, const u16* __restrict__ Bl1,
    float* __restrict__ O1)
{
  __shared__ u16 SA[3][64*32], SAL[3][64*32], SB[3][64*32], SBL[3][64*32];
  const int tid=threadIdx.x, bx=blockIdx.x;
  const int sel = blockIdx.y;
  const u16* Ah = sel? Ah1:Ah0;  const u16* Al = sel? Al1:Al0;
  const u16* BhT= sel? Bh1:Bh0;  const u16* BlT= sel? Bl1:Bl0;
  float* Out = sel? O1:O0;
  const int w=tid>>6, lane=tid&63, q4=lane>>4, l15=lane&15;
  const int bloc = bx/75;
  const u16* bh_ = BhT + (size_t)bloc*16384;
  const u16* bl_ = BlT + (size_t)bloc*16384;
  const size_t arow0 = (size_t)bx*64;
  const int rsub = lane>>2;
  const int csub = (((lane&3) ^ ((lane>>2)&3))<<3);
  f32x4 acc[4];
  #pragma unroll
  for (int t=0;t<4;t++){ acc[t][0]=0.f; acc[t][1]=0.f; acc[t][2]=0.f; acc[t][3]=0.f; }

  auto stage = [&](int k0, int buf){
    #pragma unroll
    for (int i=0;i<4;i++){
      const int row = i*16 + rsub;
      if (w==0)      gl_lds16(Ah + (arow0+row)*256 + k0 + csub, &SA [buf][i*16*32]);
      else if (w==1) gl_lds16(Al + (arow0+row)*256 + k0 + csub, &SAL[buf][i*16*32]);
      else if (w==2) gl_lds16(bh_ + (size_t)row*256 + k0 + csub, &SB [buf][i*16*32]);
      else           gl_lds16(bl_ + (size_t)row*256 + k0 + csub, &SBL[buf][i*16*32]);
    }
  };

  stage(0, 0);
  stage(32, 1);
  vm_wait4();
  __builtin_amdgcn_s_barrier();
  int cb = 0;
  for (int t=0;t<8;++t){
    if (t+2 < 8){
      int sbuf = cb ? cb-1 : 2;
      stage((t+2)*32, sbuf);
    }
    bf16x8 ah, al;
    __builtin_memcpy(&ah, &SA [cb][(w*16+l15)*32 + ((q4^(l15&3))<<3)], 16);
    __builtin_memcpy(&al, &SAL[cb][(w*16+l15)*32 + ((q4^(l15&3))<<3)], 16);
    #pragma unroll
    for (int nt=0;nt<4;nt++){
      bf16x8 bh, bl;
      __builtin_memcpy(&bh, &SB [cb][(nt*16+l15)*32 + ((q4^(l15&3))<<3)], 16);
      __builtin_memcpy(&bl, &SBL[cb][(nt*16+l15)*32 + ((q4^(l15&3))<<3)], 16);
      acc[nt] = __builtin_amdgcn_mfma_f32_16x16x32_bf16(ah, bh, acc[nt], 0,0,0);
      acc[nt] = __builtin_amdgcn_mfma_f32_16x16x32_bf16(ah, bl, acc[nt], 0,0,0);
      acc[nt] = __builtin_amdgcn_mfma_f32_16x16x32_bf16(al, bh, acc[nt], 0,0,0);
    }
    if (t+1 < 8){
      if (t+2 < 8) vm_wait4(); else vm_drain();
      __builtin_amdgcn_s_barrier();
      cb = (cb==2)? 0 : cb+1;
    }
  }
  #pragma unroll
  for (int nt=0;nt<4;nt++)
    #pragma unroll
    for (int r=0;r<4;r++)
      Out[(arow0 + w*16 + q4*4 + r)*64 + nt*16 + l15] = acc[nt][r];
}

// ---------------------------------------------------------------------------
// MFMA KV reduce: KV[bh,d,v] += sum_s K'[s,d]*V[s,v]; Ks[bh,d] += sum_s K'[s,d]
// KSM (DKT=8, KF32): K' = row-softmax(logits)*col-softmax + 1, computed inline.
// ---------------------------------------------------------------------------
template<int DKT, bool ELU, bool KF32, bool KSM>
__global__ __launch_bounds__(256) void la_reduce_mfma(
    const void* __restrict__ Kv, int kstride, const u16* __restrict__ Vv,
    float* __restrict__ KV, float* __restrict__ Ks, int Skv,
    const float* __restrict__ cmax, const float* __restrict__ csum)
{
  constexpr int PAD = 136;               // u16 row stride (272B: 16B-aligned)
  constexpr int MROW = (DKT<16)?16:DKT;
  __shared__ u16 Klt[MROW*PAD];
  __shared__ u16 Vlt[32*PAD];
  __shared__ float Ksl[DKT];
  const int tid = threadIdx.x;
  const int bh = blockIdx.y; const int b = bh>>3, h = bh&7;
  const int s0 = blockIdx.x*256;
  if (tid < DKT) Ksl[tid] = 0.f;

  const int w = tid>>6, lane = tid&63, q4 = lane>>4, l15 = lane&15;
  constexpr int NT = (DKT==32)?4:2;      // 16x16 output tiles
  const int tileid = w % NT;
  const int mt = (DKT==32)? (tileid>>1) : 0;
  const int nt = (DKT==32)? (tileid&1) : tileid;
  constexpr int KPER = (DKT==32)?4:2;    // ksteps per wave
  const int k0w = (w/NT)*KPER;

  const int kd = tid & (DKT-1);
  const int ksrow = tid / DKT;           // DKT=32: 0..7; DKT=8: 0..31
  const int ksstep = 256/DKT;
  const int vv = tid & 31, vsrow = tid >> 5;

  f32x4 acc; acc[0]=0.f; acc[1]=0.f; acc[2]=0.f; acc[3]=0.f;
  float kacc = 0.f;

  for (int cc=0; cc<2; cc++){
    const int sc0 = s0 + cc*128;
    // ---- stage K' transposed ----
    if constexpr (KSM){
      #pragma unroll
      for (int t=0; t<4; t++){
        int s = ksrow + t*32;
        float xv = 0.f;
        if (sc0+s < Skv){
          const float* rowp = (const float*)Kv + ((size_t)b*Skv + sc0+s)*64;
          float vals[8];
          #pragma unroll
          for (int j=0;j<8;j++) vals[j] = rowp[kd + 8*j];
          float m = vals[0];
          #pragma unroll
          for (int j=1;j<8;j++) m = fmaxf(m, vals[j]);
          #pragma unroll
          for (int off=1;off<8;off<<=1) m = fmaxf(m, __shfl_xor(m, off));
          float ssum = 0.f;
          #pragma unroll
          for (int j=0;j<8;j++) ssum += __expf(vals[j]-m);
          #pragma unroll
          for (int off=1;off<8;off<<=1) ssum += __shfl_xor(ssum, off);
          float vneed = vals[0];
          #pragma unroll
          for (int j=1;j<8;j++) if (h==j) vneed = vals[j];
          const int np = h*8 + kd;
          float cs = __expf(vneed - cmax[(size_t)b*64+np]) / csum[(size_t)b*64+np];
          xv = (__expf(vneed-m)/ssum)*cs + 1.f;
        }
        Klt[kd*PAD + s] = f2b(xv);
        kacc += xv;
      }
    } else {
      #pragma unroll
      for (int t=0; t<DKT/2; t++){
        int s = ksrow + t*ksstep;
        float xv = 0.f;
        if (sc0+s < Skv){
          size_t gi = ((size_t)b*Skv + sc0+s)*kstride + h*DKT + kd;
          float kk = KF32 ? ((const float*)Kv)[gi] : b2f(((const u16*)Kv)[gi]);
          xv = ELU ? (kk>0.f? kk+1.f : __expf(kk)) : kk+1.f;
        }
        Klt[kd*PAD + s] = f2b(xv);
        kacc += xv;
      }
    }
    if (DKT==8){  // zero garbage rows 8..15 for the 16-row MFMA tile
      for (int i=tid; i<8*128; i+=256){ int rr=8+(i>>7), s=i&127; Klt[rr*PAD+s]=0; }
    }
    // ---- stage V transposed ----
    #pragma unroll
    for (int t=0; t<16; t++){
      int s = vsrow + t*8;
      u16 raw = 0;
      if (sc0+s < Skv) raw = Vv[((size_t)b*Skv + sc0+s)*256 + h*32 + vv];
      Vlt[vv*PAD + s] = raw;
    }
    __syncthreads();
    // ---- MFMA over this 128-s chunk ----
    #pragma unroll
    for (int kk=0; kk<KPER; kk++){
      int ks = k0w + kk;
      bf16x8 af, bv;
      __builtin_memcpy(&af, &Klt[(mt*16+l15)*PAD + ks*32 + q4*8], 16);
      __builtin_memcpy(&bv, &Vlt[(nt*16+l15)*PAD + ks*32 + q4*8], 16);
      acc = __builtin_amdgcn_mfma_f32_16x16x32_bf16(af, bv, acc, 0,0,0);
    }
    __syncthreads();
  }
  // ---- partial stores ----
  #pragma unroll
  for (int r=0;r<4;r++){
    int row = q4*4 + r;
    if (DKT==32 || row < 8){
      int dg = mt*16 + row;
      atomicAdd(&KV[((size_t)bh*DKT + dg)*32 + nt*16 + l15], acc[r]);
    }
  }
  atomicAdd(&Ksl[kd], kacc);
  __syncthreads();
  if (tid < DKT) atomicAdd(&Ks[(size_t)bh*DKT + tid], Ksl[tid]);
}

// ---------------------------------------------------------------------------
// Small all-fp32 GEMM triple (decoder): g=bx>>7 selects (W,O). mode 0/1(relu).
// amask masks the A row index (proto-broadcast reads without expansion).
// ---------------------------------------------------------------------------
__global__ __launch_bounds__(256) void small_gemm3(
    const float* __restrict__ A,
    const float* __restrict__ W0, const float* __restrict__ W1, const float* __restrict__ W2,
    float* __restrict__ O0, float* __restrict__ O1, float* __restrict__ O2,
    int mode, int amask)
{
  __shared__ float Alds[4][256];
  const int g = blockIdx.x>>7;
  const float* W = g==0?W0:(g==1?W1:W2);
  float* Of = g==0?O0:(g==1?O1:O2);
  const int tid=threadIdx.x; const int r0=(blockIdx.x&127)*4;
  for (int i=tid;i<1024;i+=256){ int r=i>>8, c=i&255;
    Alds[r][c]=A[(size_t)((r0+r)&amask)*256+c]; }
  __syncthreads();
  float a0=0.f,a1=0.f,a2=0.f,a3=0.f;
  for (int k=0;k<256;k++){
    float w=W[(size_t)k*256+tid];
    a0+=Alds[0][k]*w; a1+=Alds[1][k]*w; a2+=Alds[2][k]*w; a3+=Alds[3][k]*w;
  }
  float accs[4]={a0,a1,a2,a3};
  #pragma unroll
  for (int r=0;r<4;r++){
    size_t idx=(size_t)(r0+r)*256+tid; float v=accs[r];
    if (mode==1) v = v>0.f?v:0.f;
    Of[idx]=v;
  }
}

// ---------------------------------------------------------------------------
// Fused decoder chain, 1 row per block (grid 512; 2 blocks/CU for TLP).
// gemmR: 16-wide double-buffered W prefetch. KV2 staged early (overlaps
// the dWqm/dWpq GEMMs). Tail Wqp/Wkp fused into one dual-output k-loop.
// ---------------------------------------------------------------------------
template<int R>
__global__ __launch_bounds__(256) void decoder_chain(
    const float* __restrict__ S1, const float* __restrict__ proq,
    const float* __restrict__ KV1, const float* __restrict__ Ks1,
    const float* __restrict__ KV2, const float* __restrict__ Ks2,
    const float* __restrict__ dWqm, const float* __restrict__ dl1g, const float* __restrict__ dl1b,
    const float* __restrict__ dWpq,
    const float* __restrict__ dWpm, const float* __restrict__ dl2g, const float* __restrict__ dl2b,
    const float* __restrict__ dWf1, const float* __restrict__ dWf2,
    const float* __restrict__ dl3g, const float* __restrict__ dl3b,
    const float* __restrict__ Wqp, const float* __restrict__ Wkp,
    float* __restrict__ ppf, float* __restrict__ pkf)
{
  __shared__ float KVl[8*32*32];     // 32 KB
  __shared__ float Ksl[8*32];
  __shared__ float rowA[R][256];
  __shared__ float rowB[R][256];
  __shared__ float red[4][R], red2[4][R];
  const int tid = threadIdx.x;
  const int r0g = blockIdx.x*R;
  const int b = r0g >> 6;
  const int h = tid>>5, vv = tid&31;
  const int w_ = tid>>6, ln_ = tid&63;

  // 16-wide double-buffered GEMM: next chunk's W loads issued before FMAs.
  auto gemmR = [&](float (*Ain)[256], const float* __restrict__ W, float* out){
    float a[R];
    #pragma unroll
    for (int r=0;r<R;r++) a[r]=0.f;
    float wv[16], wn[16];
    #pragma unroll
    for (int u=0;u<16;u++) wn[u]=0.f;
    #pragma unroll
    for (int u=0;u<16;u++) wv[u]=W[(size_t)u*256+tid];
    for (int k0=0;k0<256;k0+=16){
      if (k0+16<256){
        #pragma unroll
        for (int u=0;u<16;u++) wn[u]=W[(size_t)(k0+16+u)*256+tid];
      }
      #pragma unroll
      for (int u=0;u<16;u++){
        #pragma unroll
        for (int r=0;r<R;r++) a[r]+=Ain[r][k0+u]*wv[u];
      }
      #pragma unroll
      for (int u=0;u<16;u++) wv[u]=wn[u];
    }
    #pragma unroll
    for (int r=0;r<R;r++) out[r]=a[r];
  };
  // dual-output GEMM: one pass over A, two weight streams (tail projections).
  auto gemmR2 = [&](float (*Ain)[256], const float* __restrict__ Wa,
                    const float* __restrict__ Wb, float* oa, float* ob){
    float a[R], bacc[R];
    #pragma unroll
    for (int r=0;r<R;r++){ a[r]=0.f; bacc[r]=0.f; }
    float wa[8], wb[8], na[8], nb[8];
    #pragma unroll
    for (int u=0;u<8;u++){ wa[u]=Wa[(size_t)u*256+tid]; wb[u]=Wb[(size_t)u*256+tid]; }
    for (int k0=0;k0<256;k0+=8){
      if (k0+8<256){
        #pragma unroll
        for (int u=0;u<8;u++){ na[u]=Wa[(size_t)(k0+8+u)*256+tid]; nb[u]=Wb[(size_t)(k0+8+u)*256+tid]; }
      }
      #pragma unroll
      for (int u=0;u<8;u++){
        #pragma unroll
        for (int r=0;r<R;r++){
          float av = Ain[r][k0+u];
          a[r]+=av*wa[u]; bacc[r]+=av*wb[u];
        }
      }
      #pragma unroll
      for (int u=0;u<8;u++){ wa[u]=na[u]; wb[u]=nb[u]; }
    }
    #pragma unroll
    for (int r=0;r<R;r++){ oa[r]=a[r]; ob[r]=bacc[r]; }
  };
  // exact two-pass LN over 256 cols; trailing sync so Out is readable after.
  auto lnR = [&](float* v, const float* __restrict__ g, const float* __restrict__ be,
                 float (*Out)[256]){
    float s[R];
    #pragma unroll
    for (int r=0;r<R;r++) s[r]=v[r];
    #pragma unroll
    for (int off=32;off;off>>=1){
      #pragma unroll
      for (int r=0;r<R;r++) s[r]+=__shfl_xor(s[r],off);
    }
    if (ln_==0){
      #pragma unroll
      for (int r=0;r<R;r++) red[w_][r]=s[r];
    }
    __syncthreads();
    float mean[R];
    #pragma unroll
    for (int r=0;r<R;r++) mean[r]=(red[0][r]+red[1][r]+red[2][r]+red[3][r])*(1.f/256.f);
    float q[R];
    #pragma unroll
    for (int r=0;r<R;r++){ float d=v[r]-mean[r]; q[r]=d*d; }
    #pragma unroll
    for (int off=32;off;off>>=1){
      #pragma unroll
      for (int r=0;r<R;r++) q[r]+=__shfl_xor(q[r],off);
    }
    if (ln_==0){
      #pragma unroll
      for (int r=0;r<R;r++) red2[w_][r]=q[r];
    }
    __syncthreads();
    const float gg=g[tid], bb=be[tid];
    #pragma unroll
    for (int r=0;r<R;r++){
      float var=(red2[0][r]+red2[1][r]+red2[2][r]+red2[3][r])*(1.f/256.f);
      Out[r][tid]=(v[r]-mean[r])*rsqrtf(var+1e-5f)*gg+bb;
    }
    __syncthreads();
  };
  // linear-attention apply (DKT=32, ELU): Q rows -> Out rows. In-place safe.
  auto applyR = [&](float (*Q)[256], float (*Out)[256]){
    float res[R];
    #pragma unroll
    for (int r=0;r<R;r++){
      float z=0.f,o=0.f;
      #pragma unroll 8
      for (int d=0;d<32;d++){
        float q = Q[r][h*32+d];
        q = q>0.f? q+1.f : __expf(q);
        z += q*Ksl[h*32+d];
        o += q*KVl[(h*32+d)*32+vv];
      }
      res[r]=o/(z+1e-6f);
    }
    __syncthreads();                 // all reads of Q + KVl done before overwrite
    #pragma unroll
    for (int r=0;r<R;r++) Out[r][h*32+vv]=res[r];
    __syncthreads();
  };

  // stage: qq rows + KV1
  for (int i=tid;i<8192;i+=256) KVl[i]=KV1[(size_t)b*8192+i];
  Ksl[tid]=Ks1[(size_t)b*256+tid];
  for (int i=tid;i<R*256;i+=256){ int r=i>>8,c=i&255; rowA[r][c]=S1[(size_t)(r0g+r)*256+c]; }
  __syncthreads();
  applyR(rowA,rowB);                                   // msg_attn; KVl free after
  // stage KV2 NOW -- overlaps the next two GEMMs + LN (barrier before next apply)
  for (int i=tid;i<8192;i+=256) KVl[i]=KV2[(size_t)b*8192+i];
  Ksl[tid]=Ks2[(size_t)b*256+tid];
  float v[R], v2[R];
  gemmR(rowB,dWqm,v);
  #pragma unroll
  for (int r=0;r<R;r++) v[r]+=proq[(size_t)((r0g+r)&63)*256+tid];
  lnR(v,dl1g,dl1b,rowA);                               // rowA = msg
  gemmR(rowA,dWpq,v2);                                 // mq rows
  #pragma unroll
  for (int r=0;r<R;r++) rowB[r][tid]=v2[r];
  __syncthreads();                                     // KV2 staging + rowB visible
  applyR(rowB,rowB);                                   // proto_attn (in place)
  gemmR(rowB,dWpm,v);
  #pragma unroll
  for (int r=0;r<R;r++) v[r]+=rowA[r][tid];            // + msg residual
  lnR(v,dl2g,dl2b,rowA);                               // rowA = proto
  gemmR(rowA,dWf1,v);
  #pragma unroll
  for (int r=0;r<R;r++) rowB[r][tid]=v[r]>0.f?v[r]:0.f;
  __syncthreads();
  gemmR(rowB,dWf2,v);
  #pragma unroll
  for (int r=0;r<R;r++) v[r]+=rowA[r][tid];            // + proto residual
  lnR(v,dl3g,dl3b,rowA);                               // rowA = decoder out
  gemmR2(rowA,Wqp,Wkp,v,v2);
  #pragma unroll
  for (int r=0;r<R;r++){
    ppf[(size_t)(r0g+r)*256+tid]=v[r];
    pkf[(size_t)(r0g+r)*256+tid]=v2[r];
  }
}

// ---------------------------------------------------------------------------
// Per-batch M[c,np] = sum_j W[c,j]*P[b*64+np,j] -> TRANSPOSED hi/lo bf16.
// Dual: blockIdx.z selects (W,P,out) set. grid(8,16,2).
// ---------------------------------------------------------------------------
__global__ __launch_bounds__(256) void proj_mat2(
    const float* __restrict__ Wa, const float* __restrict__ Pa,
    u16* __restrict__ Mha, u16* __restrict__ Mla,
    const float* __restrict__ Wb, const float* __restrict__ Pb,
    u16* __restrict__ Mhb, u16* __restrict__ Mlb)
{
  __shared__ float PL[64][256];
  const float* W = blockIdx.z? Wb:Wa;
  const float* P = blockIdx.z? Pb:Pa;
  u16* MhT = blockIdx.z? Mhb:Mha;
  u16* MlT = blockIdx.z? Mlb:Mla;
  const int b = blockIdx.x, c0 = blockIdx.y*16, tid = threadIdx.x;
  for (int i=tid;i<16384;i+=256){ int row=i>>8, col=i&255;
    PL[row][col] = P[(size_t)(b*64+row)*256 + col]; }
  __syncthreads();
  const int np = tid&63, cl = tid>>6;
  #pragma unroll
  for (int rr=0;rr<4;rr++){
    int ci = cl + rr*4;
    float acc=0.f;
    for (int j=0;j<256;j++) acc += W[(size_t)(c0+ci)*256+j]*PL[np][j];
    size_t idx = (size_t)b*16384 + (size_t)np*256 + (c0+ci);
    u16 h=f2b(acc); MhT[idx]=h; MlT[idx]=f2b(acc-b2f(h));
  }
}

// ---------------------------------------------------------------------------
// Old scalar KV reduce (decoder only, fp32 in, S=64).
// ---------------------------------------------------------------------------
template<int DKT, bool ELU>
__global__ __launch_bounds__(256) void la_reduce(
    const float* __restrict__ Kv, int kstride, const float* __restrict__ Vv,
    float* __restrict__ KV, float* __restrict__ Ks, int Skv, int clen)
{
  __shared__ float Kl[64*DKT];
  __shared__ float Vl[64*32];
  const int b = blockIdx.y>>3, h = blockIdx.y&7;
  const int tid=threadIdx.x;
  const int s0 = blockIdx.x*clen; const int s1 = imin(s0+clen, Skv);
  const int d0 = tid>>5, vvv = tid&31;
  float acc[DKT/8], kac[DKT/8];
  #pragma unroll
  for (int p=0;p<DKT/8;p++){ acc[p]=0.f; kac[p]=0.f; }
  for (int sc=s0; sc<s1; sc+=64){
    int ns = imin(64, s1-sc);
    for (int i=tid;i<ns*DKT;i+=256){ int s=i/DKT, d=i-s*DKT;
      float xv = Kv[((size_t)b*Skv + sc+s)*kstride + h*DKT + d];
      Kl[s*DKT+d] = ELU ? (xv>0.f? xv+1.f : __expf(xv)) : xv+1.f; }
    for (int i=tid;i<ns*32;i+=256){ int s=i>>5, c=i&31;
      Vl[s*32+c] = Vv[((size_t)b*Skv+sc+s)*256 + h*32 + c]; }
    __syncthreads();
    for (int s=0;s<ns;s++){
      float vval = Vl[s*32+vvv];
      #pragma unroll
      for (int p=0;p<DKT/8;p++){ float kk=Kl[s*DKT + d0+8*p]; acc[p]+=kk*vval; kac[p]+=kk; }
    }
    __syncthreads();
  }
  #pragma unroll
  for (int p=0;p<DKT/8;p++)
    atomicAdd(&KV[(((size_t)b*8+h)*DKT + d0+8*p)*32 + vvv], acc[p]);
  if (vvv==0){
    #pragma unroll
    for (int p=0;p<DKT/8;p++)
      atomicAdd(&Ks[((size_t)b*8+h)*DKT + d0+8*p], kac[p]);
  }
}

// ---------------------------------------------------------------------------
// Apply: out[l,h*32+v]=(sum_d Q'[d]*KV[d,v])/(sum_d Q'[d]*Ks[d]+1e-6)
// QSM (DKT=8): Q' computed inline from raw logits.
// ---------------------------------------------------------------------------
template<int DKT, bool ELU, bool OUTBF, bool QSM>
__global__ __launch_bounds__(256) void la_apply(
    const float* __restrict__ Qsrc, const float* __restrict__ KV,
    const float* __restrict__ Ks, int Lq, float* __restrict__ outf, u16* __restrict__ outb,
    const float* __restrict__ cmax, const float* __restrict__ csum)
{
  __shared__ float KVl[8*DKT*32];
  __shared__ float Ksl[8*DKT];
  __shared__ float Ql[16*8*DKT];
  const int b = blockIdx.y; const int r0 = blockIdx.x*16;
  const int tid = threadIdx.x;
  const float* KVb = KV + (size_t)b*8*DKT*32;
  for (int i=tid;i<8*DKT*32;i+=256) KVl[i]=KVb[i];
  for (int i=tid;i<8*DKT;i+=256) Ksl[i]=Ks[(size_t)b*8*DKT + i];
  if constexpr (QSM){
    const int wv = tid>>6, ln = tid&63;
    #pragma unroll
    for (int rr=0;rr<4;rr++){
      const int r = wv*4+rr;
      float v = Qsrc[((size_t)b*Lq + r0 + r)*64 + ln];
      float m = v;
      #pragma unroll
      for (int off=32;off;off>>=1) m = fmaxf(m, __shfl_xor(m,off));
      float e = __expf(v-m);
      float s = e;
      #pragma unroll
      for (int off=32;off;off>>=1) s += __shfl_xor(s,off);
      float cs = __expf(v - cmax[(size_t)b*64+ln]) / csum[(size_t)b*64+ln];
      Ql[r*64+ln] = (e/s)*cs;
    }
  } else {
    for (int i=tid;i<16*8*DKT;i+=256){ int r=i/(8*DKT); int c=i-r*(8*DKT);
        Ql[i] = Qsrc[((size_t)b*Lq + r0 + r)*(8*DKT) + c]; }
  }
  __syncthreads();
  const int h = tid>>5, vv = tid&31;
  for (int r=0;r<16;r++){
    float z=0.f, o=0.f;
    #pragma unroll
    for (int d=0; d<DKT; d++){
      float q = Ql[r*8*DKT + h*DKT + d];
      q = ELU ? (q>0.f? q+1.f : __expf(q)) : q+1.f;
      z += q*Ksl[h*DKT+d];
      o += q*KVl[(h*DKT+d)*32 + vv];
    }
    float res = o/(z+1e-6f);
    size_t idx = ((size_t)b*Lq + r0+r)*256 + h*32+vv;
    if (OUTBF) outb[idx]=f2b(res); else outf[idx]=res;
  }
}

// ---------------------------------------------------------------------------
// LayerNorm over 256, eps=1e-5 — wave-per-row, vectorized, no LDS/barriers.
// MODE 1: bf16 LN(A)->Ob in-place; MODE 2: fp32 xadd + LN(A)->Ox, A bf16 if ABF.
// Grid = rows/4.
// ---------------------------------------------------------------------------
template<int MODE, bool ABF>
__global__ __launch_bounds__(256) void ln_kernel(
  const void* __restrict__ Av, const float* __restrict__ resid,
  const float* __restrict__ g, const float* __restrict__ be,
  float* __restrict__ Of, u16* __restrict__ Ob, const float* __restrict__ xadd,
  float* __restrict__ Ox)
{
  const int tid = threadIdx.x;
  const size_t row = (size_t)blockIdx.x*4 + (tid>>6);
  const int lane = tid&63;
  const int c0 = lane<<2;
  const size_t gi = row*256 + c0;
  float v[4];
  if (MODE==1 || ABF){
    ushort4 u = *(const ushort4*)((const u16*)Av + gi);
    v[0]=b2f(u.x); v[1]=b2f(u.y); v[2]=b2f(u.z); v[3]=b2f(u.w);
  } else {
    float4 f = *(const float4*)((const float*)Av + gi);
    v[0]=f.x; v[1]=f.y; v[2]=f.z; v[3]=f.w;
  }
  if (MODE==0){
    float4 r = *(const float4*)(resid + gi);
    v[0]+=r.x; v[1]+=r.y; v[2]+=r.z; v[3]+=r.w;
  }
  float s = v[0]+v[1]+v[2]+v[3];
  #pragma unroll
  for (int off=32;off;off>>=1) s += __shfl_xor(s,off);
  const float mean = s*(1.f/256.f);
  float d[4]; float qq=0.f;
  #pragma unroll
  for (int i=0;i<4;i++){ d[i]=v[i]-mean; qq += d[i]*d[i]; }
  #pragma unroll
  for (int off=32;off;off>>=1) qq += __shfl_xor(qq,off);
  const float rstd = rsqrtf(qq*(1.f/256.f)+1e-5f);
  const float4 gv = *(const float4*)(g+c0);
  const float4 bv = *(const float4*)(be+c0);
  float y[4];
  y[0]=d[0]*rstd*gv.x+bv.x; y[1]=d[1]*rstd*gv.y+bv.y;
  y[2]=d[2]*rstd*gv.z+bv.z; y[3]=d[3]*rstd*gv.w+bv.w;
  if (MODE==0){
    *(float4*)(Of+gi) = make_float4(y[0],y[1],y[2],y[3]);
  } else if (MODE==1){
    ushort4 o; o.x=f2b(y[0]); o.y=f2b(y[1]); o.z=f2b(y[2]); o.w=f2b(y[3]);
    *(ushort4*)(Ob+gi)=o;
  } else {
    const float4 xa = *(const float4*)(xadd+gi);
    *(float4*)(Ox+gi) = make_float4(xa.x+y[0], xa.y+y[1], xa.z+y[2], xa.w+y[3]);
  }
}

// ---------------------------------------------------------------------------
// Column softmax stats over axis=1 (4800 rows/batch), dual: grid(64, NB, 2).
// ---------------------------------------------------------------------------
__global__ __launch_bounds__(256) void col_stats(
    const float* __restrict__ logits0, float* __restrict__ cmax0, float* __restrict__ csum0,
    const float* __restrict__ logits1, float* __restrict__ cmax1, float* __restrict__ csum1)
{
  int np = blockIdx.x, b = blockIdx.y;
  const float* logits = blockIdx.z? logits1:logits0;
  float* cmax = blockIdx.z? cmax1:cmax0;
  float* csum = blockIdx.z? csum1:csum0;
  const float* base = logits + ((size_t)b*4800)*64 + np;
  int tid = threadIdx.x;
  float vloc[19];
  float m = -3.0e38f;
  #pragma unroll
  for (int i=0;i<19;i++){ int l = tid + i*256;
    float v = (l<4800)? base[(size_t)l*64] : -3.0e38f;
    vloc[i]=v; m = fmaxf(m,v); }
  #pragma unroll
  for (int off=32;off;off>>=1) m = fmaxf(m, __shfl_xor(m,off));
  __shared__ float red[4], red2[4];
  int w = tid>>6, ln = tid&63;
  if (ln==0) red[w]=m;
  __syncthreads();
  m = fmaxf(fmaxf(red[0],red[1]), fmaxf(red[2],red[3]));
  float s=0.f;
  #pragma unroll
  for (int i=0;i<19;i++){ int l = tid + i*256; if (l<4800) s += __expf(vloc[i]-m); }
  #pragma unroll
  for (int off=32;off;off>>=1) s += __shfl_xor(s,off);
  if (ln==0) red2[w]=s;
  __syncthreads();
  s = red2[0]+red2[1]+red2[2]+red2[3];
  if (tid==0){ cmax[b*64+np]=m; csum[b*64+np]=s; }
}

// ---------------------------------------------------------------------------
extern "C" void kernel_launch(void* const* d_in, const int* in_sizes, int n_in,
                              void* d_out, int out_size, void* d_ws, size_t ws_size,
                              hipStream_t stream) {
  (void)in_sizes; (void)n_in; (void)out_size; (void)ws_size;
  const float* x    = (const float*)d_in[0];
  const float* srcp = (const float*)d_in[1];
  const float* Wq   = (const float*)d_in[4];
  const float* Wk   = (const float*)d_in[5];
  const float* Wv   = (const float*)d_in[6];
  const float* Wqp  = (const float*)d_in[7];
  const float* Wkp  = (const float*)d_in[8];
  const float* Wmg  = (const float*)d_in[9];
  const float* Wm1  = (const float*)d_in[10];
  const float* Wm2  = (const float*)d_in[11];
  const float* ln1g = (const float*)d_in[12];
  const float* ln1b = (const float*)d_in[13];
  const float* ln2g = (const float*)d_in[14];
  const float* ln2b = (const float*)d_in[15];
  const float* proq = (const float*)d_in[16];
  const float* dWqq = (const float*)d_in[17];
  const float* dWqk = (const float*)d_in[18];
  const float* dWqv = (const float*)d_in[19];
  const float* dWqm = (const float*)d_in[20];
  const float* dl1g = (const float*)d_in[21];
  const float* dl1b = (const float*)d_in[22];
  const float* dWpq = (const float*)d_in[23];
  const float* dWpk = (const float*)d_in[24];
  const float* dWpv = (const float*)d_in[25];
  const float* dWpm = (const float*)d_in[26];
  const float* dWf1 = (const float*)d_in[29];
  const float* dWf2 = (const float*)d_in[30];
  const float* dl3g = (const float*)d_in[31];
  const float* dl3b = (const float*)d_in[32];
  const float* dl2g = (const float*)d_in[27];
  const float* dl2b = (const float*)d_in[28];

  char* p=(char*)d_ws;
  auto alloc=[&](size_t n)->char*{ char* r=p; p+=((n+255)&~(size_t)255); return r; };
  u16* xb  = (u16*)alloc(19660800);   // x bf16 hi
  u16* xlo = (u16*)alloc(19660800);   // x bf16 lo residual
  u16* sb  = (u16*)alloc(19660800);   // source bf16 hi
  u16* slo = (u16*)alloc(19660800);   // source bf16 lo
  u16* bufA= (u16*)alloc(19660800);   // fk
  u16* bufB= (u16*)alloc(19660800);   // fv -> msg0b
  u16* v0b = (u16*)alloc(19660800);   // v0 (computed in TRI launch)
  u16* msg1b=(u16*)alloc(19660800);   // merge out bf16
  u16* h1  = (u16*)alloc(39321600);   // MLP hidden bf16 [38400,512]
  u16* mlp2b=(u16*)alloc(19660800);   // MLP out bf16
  float* qsm=(float*)alloc(9830400);  // q logits fp32 [38400,64]
  float* ksm=(float*)alloc(9830400);  // k logits fp32 [38400,64]
  u16* dWpkT=(u16*)alloc(131072); u16* dWpvT=(u16*)alloc(131072);
  u16* WvT  =(u16*)alloc(131072); u16* WmgT =(u16*)alloc(131072);
  u16* Wm1T =(u16*)alloc(524288); u16* Wm2T =(u16*)alloc(262144);
  float* S0=(float*)alloc(524288); float* S1=(float*)alloc(524288);
  float* S2=(float*)alloc(524288); float* S3=(float*)alloc(524288);
  float* S4=(float*)alloc(524288); float* S5=(float*)alloc(524288);
  float* ppf=(float*)alloc(524288); float* pkf=(float*)alloc(524288);
  u16* Mqh=(u16*)alloc(262144); u16* Mql=(u16*)alloc(262144);
  u16* Mkh=(u16*)alloc(262144); u16* Mkl=(u16*)alloc(262144);
  char* z0=p;
  float* KV1=(float*)alloc(262144); float* Ks1=(float*)alloc(8192);
  float* KV2=(float*)alloc(262144); float* Ks2=(float*)alloc(8192);
  float* KVm=(float*)alloc(65536);  float* Ksm=(float*)alloc(2048);
  char* z1=p;
  float* cmq=(float*)alloc(2048); float* csq=(float*)alloc(2048);
  float* cmk=(float*)alloc(2048); float* csk=(float*)alloc(2048);
  (void)S4; (void)S5;

  u16* fk=bufA;
  u16* fv=bufB; u16* msg0b=bufB;
  float* dof=(float*)d_out;

  hipMemsetAsync(z0, 0, (size_t)(z1-z0), stream);

  dim3 blk(256);
  // ---- phase 0: splits + weight transposes ----
  cvt_split2<<<dim3(19200),blk,0,stream>>>(x, xb, xlo, srcp, sb, slo, 9830400);
  wtrans4<<<dim3(256,4),blk,0,stream>>>(dWpk,dWpv,Wv,Wmg, dWpkT,dWpvT,WvT,WmgT);
  wtrans2<<<dim3(1536),blk,0,stream>>>(Wm1, Wm1T, Wm2, Wm2T);
  // ---- phase 1: fk, fv AND v0 in one TRI launch, then MFMA KV reduce ----
  gemm128<256,1,false,3><<<dim3(300,2,3),blk,0,stream>>>(
      xb,nullptr,sb, dWpkT,dWpvT,WvT, nullptr, fk,fv,v0b, 256,0);
  la_reduce_mfma<32,true,false,false><<<dim3(19,64),blk,0,stream>>>(
      fk,256,fv,KV2,Ks2,4800,nullptr,nullptr);
  // ---- phase 2: DETR decoder, fully fused; warm chain weights into every
  //      XCD L2 right before the chain ----
  small_gemm3<<<dim3(384),blk,0,stream>>>(proq,dWqq,dWqk,dWqv,S1,S2,S3,0,63);
  la_reduce<32,true><<<dim3(1,64),blk,0,stream>>>(S2,256,S3,KV1,Ks1,64,64);
  warm7<<<dim3(3584),blk,0,stream>>>(dWqm,dWpq,dWpm,dWf1,dWf2,Wqp,Wkp,S0);
  decoder_chain<1><<<dim3(512),blk,0,stream>>>(
      S1,proq, KV1,Ks1, KV2,Ks2,
      dWqm,dl1g,dl1b, dWpq, dWpm,dl2g,dl2b, dWf1,dWf2,dl3g,dl3b,
      Wqp,Wkp, ppf,pkf);
  // ---- phase 3: folded reprojection matrices (dual, one launch) ----
  proj_mat2<<<dim3(8,16,2),blk,0,stream>>>(Wq,ppf,Mqh,Mql, Wk,pkf,Mkh,Mkl);
  // ---- phase 4: logits (dual) + col stats (dual); row softmax fused into
  //      consumers (la_apply / la_reduce_mfma) ----
  gemm_logits2<<<dim3(600,2),blk,0,stream>>>(xb,xlo,Mqh,Mql,qsm, sb,slo,Mkh,Mkl,ksm);
  col_stats<<<dim3(64,8,2),blk,0,stream>>>(qsm,cmq,csq, ksm,cmk,csk);
  // ---- phase 5: main MFMA KV reduce (k-softmax inline; v0 from phase 1) ----
  la_reduce_mfma<8,false,true,true><<<dim3(19,64),blk,0,stream>>>(
      ksm,64,v0b,KVm,Ksm,4800,cmk,csk);
  // ---- phase 6: apply (q-softmax inline) + merge + LN1 ----
  la_apply<8,false,true,true><<<dim3(300,8),blk,0,stream>>>(
      qsm,KVm,Ksm,4800,nullptr,msg0b,cmq,csq);
  gemm128<256,1,false,1><<<dim3(300,2),blk,0,stream>>>(
      msg0b,nullptr,nullptr, WmgT,nullptr,nullptr, nullptr, msg1b,nullptr,nullptr, 256,0);
  ln_kernel<1,false><<<dim3(9600),blk,0,stream>>>(msg1b,nullptr,ln1g,ln1b,nullptr,msg1b,nullptr,nullptr);
  // ---- phase 7: MLP (cat inside) + LN2 + residual ----
  gemm128<512,2,true,1><<<dim3(300,4),blk,0,stream>>>(
      xb,msg1b,nullptr, Wm1T,nullptr,nullptr, nullptr, h1,nullptr,nullptr, 512,0);
  gemm128<512,1,false,1><<<dim3(300,2),blk,0,stream>>>(
      h1,nullptr,nullptr, Wm2T,nullptr,nullptr, nullptr, mlp2b,nullptr,nullptr, 256,0);
  ln_kernel<2,true><<<dim3(9600),blk,0,stream>>>(mlp2b,nullptr,ln2g,ln2b,nullptr,nullptr,x,dof);
}